// Round 5
// baseline (499.038 us; speedup 1.0000x reference)
//
#include <hip/hip_runtime.h>
#include <hip/hip_cooperative_groups.h>
#include <math.h>

namespace cg = cooperative_groups;

#define N_PTS 1024
#define HID   256
#define FEAT  2048

typedef short bf16x8 __attribute__((ext_vector_type(8)));
typedef float f32x4  __attribute__((ext_vector_type(4)));

__device__ inline ushort f2bf(float f) {
    union { float f; unsigned u; } v; v.f = f;
    unsigned r = v.u + 0x7fff + ((v.u >> 16) & 1);   // round-to-nearest-even
    return (ushort)(r >> 16);
}

// train-mode BN (biased var) + ReLU from raw column sums
__device__ inline float bnrelu(float v, float s, float q, float g, float b) {
    float m   = s * (1.f / 1024.f);
    float var = fmaf(-m, m, q * (1.f / 1024.f));
    float sc  = g * rsqrtf(var + 1e-5f);
    return fmaxf(fmaf(v, sc, fmaf(-sc, m, b)), 0.f);
}

// one 64x64 output tile, BK=64, 4 waves in 2x2; optional BN+ReLU on A from
// raw stats; B pre-transposed bf16 [n][ldb]; fp32 atomic epilogue (split-K).
__device__ void gemm_tile(
    const ushort* __restrict__ Abf, const float* __restrict__ Afp,
    const float* __restrict__ sum, const float* __restrict__ sq,
    const float* __restrict__ g, const float* __restrict__ bt,
    const ushort* __restrict__ Bt, float* __restrict__ C,
    int lda, int ldb, int ldc, int mBase, int nBase, int kBeg, int kIters,
    char* smraw)
{
    ushort* As = (ushort*)smraw;            // 64*72 ushorts
    ushort* Bs = (ushort*)(smraw + 9216);
    const int tid  = threadIdx.x;
    const int lane = tid & 63, wave = tid >> 6;
    const int wy = wave >> 1, wx = wave & 1;
    const int quad = lane >> 4, l16 = lane & 15;

    f32x4 acc[2][2] = {};

    for (int it = 0; it < kIters; ++it) {
        const int ks = kBeg + it * 64;
        if (Afp) {
            #pragma unroll
            for (int p = 0; p < 4; p++) {
                const int c = p * 256 + tid, r = c >> 4, q = c & 15;
                float4 v  = *(const float4*)&Afp[(size_t)(mBase + r) * lda + ks + q * 4];
                float4 sv = *(const float4*)&sum[ks + q * 4];
                float4 qv = *(const float4*)&sq[ks + q * 4];
                float4 gv = *(const float4*)&g[ks + q * 4];
                float4 bv = *(const float4*)&bt[ks + q * 4];
                ushort4 o;
                o.x = f2bf(bnrelu(v.x, sv.x, qv.x, gv.x, bv.x));
                o.y = f2bf(bnrelu(v.y, sv.y, qv.y, gv.y, bv.y));
                o.z = f2bf(bnrelu(v.z, sv.z, qv.z, gv.z, bv.z));
                o.w = f2bf(bnrelu(v.w, sv.w, qv.w, gv.w, bv.w));
                *(ushort4*)&As[r * 72 + q * 4] = o;
            }
        } else {
            #pragma unroll
            for (int p = 0; p < 2; p++) {
                const int c = p * 256 + tid, r = c >> 3, q = c & 7;
                *(bf16x8*)&As[r * 72 + q * 8] =
                    *(const bf16x8*)&Abf[(size_t)(mBase + r) * lda + ks + q * 8];
            }
        }
        #pragma unroll
        for (int p = 0; p < 2; p++) {
            const int c = p * 256 + tid, r = c >> 3, q = c & 7;
            *(bf16x8*)&Bs[r * 72 + q * 8] =
                *(const bf16x8*)&Bt[(size_t)(nBase + r) * ldb + ks + q * 8];
        }
        __syncthreads();
        #pragma unroll
        for (int kt = 0; kt < 64; kt += 32) {
            bf16x8 af[2], bfr[2];
            #pragma unroll
            for (int mi = 0; mi < 2; mi++)
                af[mi] = *(bf16x8*)&As[(wy * 32 + mi * 16 + l16) * 72 + kt + quad * 8];
            #pragma unroll
            for (int ni = 0; ni < 2; ni++)
                bfr[ni] = *(bf16x8*)&Bs[(wx * 32 + ni * 16 + l16) * 72 + kt + quad * 8];
            #pragma unroll
            for (int mi = 0; mi < 2; mi++)
                #pragma unroll
                for (int ni = 0; ni < 2; ni++)
                    acc[mi][ni] = __builtin_amdgcn_mfma_f32_16x16x32_bf16(
                        af[mi], bfr[ni], acc[mi][ni], 0, 0, 0);
        }
        __syncthreads();
    }
    // C/D layout: col = lane&15, row = quad*4 + e
    #pragma unroll
    for (int mi = 0; mi < 2; mi++)
        #pragma unroll
        for (int ni = 0; ni < 2; ni++)
            #pragma unroll
            for (int e = 0; e < 4; e++) {
                const int gm = mBase + wy * 32 + mi * 16 + quad * 4 + e;
                const int gn = nBase + wx * 32 + ni * 16 + l16;
                unsafeAtomicAdd(&C[(size_t)gm * ldc + gn], acc[mi][ni][e]);
            }
}

__global__ __launch_bounds__(256, 2) void fused_all(
    const float* __restrict__ features, const int* __restrict__ labels,
    const float* __restrict__ W1, const float* __restrict__ g1,
    const float* __restrict__ bt1, const float* __restrict__ W2,
    const float* __restrict__ g2, const float* __restrict__ bt2,
    const float* __restrict__ We1, const float* __restrict__ bwe1,
    const float* __restrict__ We2, const float* __restrict__ bwe2,
    float* __restrict__ out, float* __restrict__ ws)
{
    __shared__ __align__(16) char smraw[18464];
    cg::grid_group grid = cg::this_grid();
    const int b = blockIdx.x, tid = threadIdx.x;

    float*  x1   = ws;                       // 262144
    float*  x2   = ws + 262144;              // 262144
    float*  hic  = ws + 524288;              // 524288 (hi | hj, ldc=512)
    float*  sum1 = ws + 1048576;             // stats: sum1 sq1 sum2 sq2
    float*  sq1  = sum1 + 256;
    float*  sum2 = sum1 + 512;
    float*  sq2  = sum1 + 768;
    ushort* featbf = (ushort*)(ws + 1049600);   // 1024x2048 bf16
    ushort* Wt1    = (ushort*)(ws + 2098176);   // 256x2048 bf16 [n][k]
    ushort* Wt2    = (ushort*)(ws + 2360320);   // 256x256
    ushort* Wt34   = (ushort*)(ws + 2393088);   // 512x256

    // ---------- phase 0: convert features, transpose weights, zero ----------
    {
        const int base = b * 4096 + tid * 16;
        #pragma unroll
        for (int q = 0; q < 4; q++) {
            float4 v = *(const float4*)&features[base + q * 4];
            ushort4 o;
            o.x = f2bf(v.x); o.y = f2bf(v.y); o.z = f2bf(v.z); o.w = f2bf(v.w);
            *(ushort4*)&featbf[base + q * 4] = o;
        }
        if (b < 176) {
            ushort* T = (ushort*)smraw;
            const float* src; ushort* dst; int Kd, kt, nt;
            if (b < 128)      { src = W1;  dst = Wt1;  Kd = 2048; kt = b >> 2; nt = b & 3; }
            else if (b < 144) { int q = b - 128; src = W2;  dst = Wt2;  Kd = 256; kt = q >> 2; nt = q & 3; }
            else if (b < 160) { int q = b - 144; src = We1; dst = Wt34; Kd = 256; kt = q >> 2; nt = q & 3; }
            else              { int q = b - 160; src = We1 + 65536; dst = Wt34 + 65536;
                                Kd = 256; kt = q >> 2; nt = q & 3; }
            const int k0 = kt * 64, n0 = nt * 64;
            #pragma unroll
            for (int p = 0; p < 4; p++) {
                const int c = p * 256 + tid, r = c >> 4, q2 = c & 15;
                float4 v = *(const float4*)&src[(size_t)(k0 + r) * 256 + n0 + q2 * 4];
                T[(q2 * 4 + 0) * 72 + r] = f2bf(v.x);
                T[(q2 * 4 + 1) * 72 + r] = f2bf(v.y);
                T[(q2 * 4 + 2) * 72 + r] = f2bf(v.z);
                T[(q2 * 4 + 3) * 72 + r] = f2bf(v.w);
            }
            __syncthreads();
            #pragma unroll
            for (int p = 0; p < 2; p++) {
                const int c = p * 256 + tid, r = c >> 3, q2 = c & 7;
                *(bf16x8*)&dst[(size_t)(n0 + r) * Kd + k0 + q2 * 8] =
                    *(bf16x8*)&T[r * 72 + q2 * 8];
            }
        } else {
            // zero x1,x2,hic,stats = 1049600 floats = 262400 float4
            float4 z = make_float4(0.f, 0.f, 0.f, 0.f);
            for (int idx = (b - 176) * 256 + tid; idx < 262400; idx += 336 * 256)
                ((float4*)ws)[idx] = z;
        }
    }
    grid.sync();

    // ---------- phase 1: x1 = featbf @ Wt1^T (64 tiles x z8) ----------
    {
        const int z = b >> 6, rem = b & 63;
        gemm_tile(featbf, nullptr, nullptr, nullptr, nullptr, nullptr,
                  Wt1, x1, FEAT, FEAT, HID,
                  (rem >> 2) * 64, (rem & 3) * 64, z * 256, 4, smraw);
    }
    grid.sync();

    // ---------- phase 2: column stats of x1 ----------
    {
        const int r0 = b * 2;
        float v0 = x1[r0 * HID + tid], v1 = x1[(r0 + 1) * HID + tid];
        unsafeAtomicAdd(&sum1[tid], v0 + v1);
        unsafeAtomicAdd(&sq1[tid], fmaf(v0, v0, v1 * v1));
    }
    grid.sync();

    // ---------- phase 3: x2 = bnrelu(x1) @ Wt2^T (64 tiles x z4) ----------
    if (b < 256) {
        const int z = b >> 6, rem = b & 63;
        gemm_tile(nullptr, x1, sum1, sq1, g1, bt1,
                  Wt2, x2, HID, HID, HID,
                  (rem >> 2) * 64, (rem & 3) * 64, z * 64, 1, smraw);
    }
    grid.sync();

    // ---------- phase 4: column stats of x2 ----------
    {
        const int r0 = b * 2;
        float v0 = x2[r0 * HID + tid], v1 = x2[(r0 + 1) * HID + tid];
        unsafeAtomicAdd(&sum2[tid], v0 + v1);
        unsafeAtomicAdd(&sq2[tid], fmaf(v0, v0, v1 * v1));
    }
    grid.sync();

    // ---------- phase 5: hic = bnrelu(x2) @ Wt34^T (128 tiles x z4) --------
    {
        const int z = b >> 7, rem = b & 127;
        gemm_tile(nullptr, x2, sum2, sq2, g2, bt2,
                  Wt34, hic, HID, HID, 512,
                  (rem >> 3) * 64, (rem & 7) * 64, z * 64, 1, smraw);
    }
    grid.sync();

    // ---------- phase 6: all-pairs edge weights + node update -------------
    {
        int*   slab  = (int*)smraw;                 // 1024 ints
        float* sacc  = (float*)(smraw + 4096);      // 4 x 256 floats
        float* swsum = (float*)(smraw + 8192);      // 4 floats
        const int lane = tid & 63, wave = tid >> 6;
        for (int t = tid; t < N_PTS; t += 256) slab[t] = labels[t];

        // per-lane BN2 scale/shift for cols 4*lane..4*lane+3
        float4 sv = *(const float4*)&sum2[lane * 4];
        float4 qv = *(const float4*)&sq2[lane * 4];
        float4 gv = *(const float4*)&g2[lane * 4];
        float4 bv = *(const float4*)&bt2[lane * 4];
        float4 sc, sh;
        {
            float m, var;
            m = sv.x * (1.f/1024.f); var = fmaf(-m, m, qv.x * (1.f/1024.f));
            sc.x = gv.x * rsqrtf(var + 1e-5f); sh.x = fmaf(-sc.x, m, bv.x);
            m = sv.y * (1.f/1024.f); var = fmaf(-m, m, qv.y * (1.f/1024.f));
            sc.y = gv.y * rsqrtf(var + 1e-5f); sh.y = fmaf(-sc.y, m, bv.y);
            m = sv.z * (1.f/1024.f); var = fmaf(-m, m, qv.z * (1.f/1024.f));
            sc.z = gv.z * rsqrtf(var + 1e-5f); sh.z = fmaf(-sc.z, m, bv.z);
            m = sv.w * (1.f/1024.f); var = fmaf(-m, m, qv.w * (1.f/1024.f));
            sc.w = gv.w * rsqrtf(var + 1e-5f); sh.w = fmaf(-sc.w, m, bv.w);
        }
        float4 bw = ((const float4*)bwe1)[lane];
        float4 w2 = ((const float4*)We2)[lane];
        const float b2 = bwe2[0];
        __syncthreads();

        for (int ii = 0; ii < 2; ii++) {
            const int i = b * 2 + ii;
            const int myLab = slab[i];
            float4 hv_i = *(const float4*)&hic[(size_t)i * 512 + lane * 4];
            const float hb0 = hv_i.x + bw.x, hb1 = hv_i.y + bw.y;
            const float hb2 = hv_i.z + bw.z, hb3 = hv_i.w + bw.w;

            float a0 = 0.f, a1 = 0.f, a2 = 0.f, a3 = 0.f, wsum = 0.f;
            for (int chunk = wave * 64; chunk < N_PTS; chunk += 256) {
                const int j = chunk + lane;
                const bool match = (slab[j] == myLab) && (j != i);
                unsigned long long mask = __ballot(match);
                while (mask) {
                    const int p0i = __builtin_ctzll(mask);
                    mask &= mask - 1;
                    const int jj0 = chunk + p0i;
                    const bool dual = (mask != 0ull);
                    int jj1 = jj0;
                    if (dual) {
                        const int p1i = __builtin_ctzll(mask);
                        mask &= mask - 1;
                        jj1 = chunk + p1i;
                    }
                    float4 hv0 = *(const float4*)&hic[(size_t)jj0 * 512 + 256 + lane * 4];
                    float4 hv1 = *(const float4*)&hic[(size_t)jj1 * 512 + 256 + lane * 4];
                    float p0 = fmaxf(hb0 + hv0.x, 0.f) * w2.x
                             + fmaxf(hb1 + hv0.y, 0.f) * w2.y
                             + fmaxf(hb2 + hv0.z, 0.f) * w2.z
                             + fmaxf(hb3 + hv0.w, 0.f) * w2.w;
                    float p1 = fmaxf(hb0 + hv1.x, 0.f) * w2.x
                             + fmaxf(hb1 + hv1.y, 0.f) * w2.y
                             + fmaxf(hb2 + hv1.z, 0.f) * w2.z
                             + fmaxf(hb3 + hv1.w, 0.f) * w2.w;
                    #pragma unroll
                    for (int off = 1; off < 64; off <<= 1) {
                        p0 += __shfl_xor(p0, off, 64);
                        p1 += __shfl_xor(p1, off, 64);
                    }
                    const float w0 = 1.f / (1.f + expf(-(p0 + b2)));
                    const float w1 = dual ? 1.f / (1.f + expf(-(p1 + b2))) : 0.f;
                    float4 xv0 = *(const float4*)&x2[(size_t)jj0 * HID + lane * 4];
                    float4 xv1 = *(const float4*)&x2[(size_t)jj1 * HID + lane * 4];
                    a0 = fmaf(w0, fmaxf(fmaf(xv0.x, sc.x, sh.x), 0.f),
                         fmaf(w1, fmaxf(fmaf(xv1.x, sc.x, sh.x), 0.f), a0));
                    a1 = fmaf(w0, fmaxf(fmaf(xv0.y, sc.y, sh.y), 0.f),
                         fmaf(w1, fmaxf(fmaf(xv1.y, sc.y, sh.y), 0.f), a1));
                    a2 = fmaf(w0, fmaxf(fmaf(xv0.z, sc.z, sh.z), 0.f),
                         fmaf(w1, fmaxf(fmaf(xv1.z, sc.z, sh.z), 0.f), a2));
                    a3 = fmaf(w0, fmaxf(fmaf(xv0.w, sc.w, sh.w), 0.f),
                         fmaf(w1, fmaxf(fmaf(xv1.w, sc.w, sh.w), 0.f), a3));
                    wsum += w0 + w1;
                }
            }
            ((float4*)&sacc[wave * HID])[lane] = make_float4(a0, a1, a2, a3);
            if (lane == 0) swsum[wave] = wsum;
            __syncthreads();
            const float at = sacc[tid] + sacc[HID + tid] +
                             sacc[2 * HID + tid] + sacc[3 * HID + tid];
            const float wt = swsum[0] + swsum[1] + swsum[2] + swsum[3];
            // di[i][tid] recomputed from stats (scalar)
            float m  = sum2[tid] * (1.f/1024.f);
            float vr = fmaf(-m, m, sq2[tid] * (1.f/1024.f));
            float s  = g2[tid] * rsqrtf(vr + 1e-5f);
            float di_i = fmaxf(fmaf(x2[(size_t)i * HID + tid], s,
                                    fmaf(-s, m, bt2[tid])), 0.f);
            out[(size_t)i * HID + tid] = di_i + (wt > 0.f ? at / wt : 0.f);
            __syncthreads();
        }
    }
}

extern "C" void kernel_launch(void* const* d_in, const int* in_sizes, int n_in,
                              void* d_out, int out_size, void* d_ws, size_t ws_size,
                              hipStream_t stream)
{
    const float* features = (const float*)d_in[0];
    const int*   labels   = (const int*)d_in[1];
    const float* W1   = (const float*)d_in[2];
    // b1/b2 cancel exactly through train-mode BN (mean subtraction)
    const float* g1   = (const float*)d_in[4];
    const float* bt1  = (const float*)d_in[5];
    const float* W2   = (const float*)d_in[6];
    const float* g2   = (const float*)d_in[8];
    const float* bt2  = (const float*)d_in[9];
    const float* We1  = (const float*)d_in[10];
    const float* bwe1 = (const float*)d_in[11];
    const float* We2  = (const float*)d_in[12];
    const float* bwe2 = (const float*)d_in[13];
    float* out = (float*)d_out;
    float* wsp = (float*)d_ws;

    void* kargs[] = { &features, &labels, &W1, &g1, &bt1, &W2, &g2, &bt2,
                      &We1, &bwe1, &We2, &bwe2, &out, &wsp };
    hipLaunchCooperativeKernel((const void*)fused_all, dim3(512), dim3(256),
                               kargs, 0, stream);
}

// Round 7
// 485.518 us; speedup vs baseline: 1.0278x; 1.0278x over previous
//
#include <hip/hip_runtime.h>
#include <math.h>

#define N_PTS 1024
#define HID   256
#define FEAT  2048
#define NBLK  512

typedef short bf16x8 __attribute__((ext_vector_type(8)));
typedef float f32x4  __attribute__((ext_vector_type(4)));

__device__ inline ushort f2bf(float f) {
    union { float f; unsigned u; } v; v.f = f;
    unsigned r = v.u + 0x7fff + ((v.u >> 16) & 1);   // round-to-nearest-even
    return (ushort)(r >> 16);
}

// train-mode BN (biased var) + ReLU from raw column sums
__device__ inline float bnrelu(float v, float s, float q, float g, float b) {
    float m   = s * (1.f / 1024.f);
    float var = fmaf(-m, m, q * (1.f / 1024.f));
    float sc  = g * rsqrtf(var + 1e-5f);
    return fmaxf(fmaf(v, sc, fmaf(-sc, m, b)), 0.f);
}

// hand-rolled grid barrier: monotonic counter (zeroed by init kernel).
// All NBLK blocks co-resident (launch_bounds(256,2) -> 2 blocks/CU x 256 CU).
__device__ __forceinline__ void gbar(unsigned* bar, unsigned target) {
    __syncthreads();
    if (threadIdx.x == 0) {
        __hip_atomic_fetch_add(bar, 1u, __ATOMIC_RELEASE, __HIP_MEMORY_SCOPE_AGENT);
        while (__hip_atomic_load(bar, __ATOMIC_ACQUIRE, __HIP_MEMORY_SCOPE_AGENT) < target)
            __builtin_amdgcn_s_sleep(2);
    }
    __syncthreads();
}

// zero barrier counter + stats (sum1,sq1,sum2,sq2 = 1024 floats)
__global__ void init_bar(unsigned* __restrict__ bar, float* __restrict__ stats) {
    ((float4*)stats)[threadIdx.x] = make_float4(0.f, 0.f, 0.f, 0.f);
    if (threadIdx.x == 0) *bar = 0u;
}

// one 64x64 output tile, BK=64, 4 waves in 2x2. Optional BN+ReLU on A from
// raw stats. B pre-transposed bf16 [n][ldb].
// atomicEp=true: unsafeAtomicAdd (split-K). false: plain store, plus exact
// column stats (sum/sumsq) into sumOut/sqOut if non-null (final values).
__device__ void gemm_tile(
    const ushort* __restrict__ Abf, const float* __restrict__ Afp,
    const float* __restrict__ sum, const float* __restrict__ sq,
    const float* __restrict__ g, const float* __restrict__ bt,
    const ushort* __restrict__ Bt, float* __restrict__ C,
    int lda, int ldb, int ldc, int mBase, int nBase, int kBeg, int kIters,
    char* smraw, bool atomicEp, float* sumOut, float* sqOut)
{
    ushort* As = (ushort*)smraw;            // 64*72 ushorts
    ushort* Bs = (ushort*)(smraw + 9216);
    const int tid  = threadIdx.x;
    const int lane = tid & 63, wave = tid >> 6;
    const int wy = wave >> 1, wx = wave & 1;
    const int quad = lane >> 4, l16 = lane & 15;

    f32x4 acc[2][2] = {};

    for (int it = 0; it < kIters; ++it) {
        const int ks = kBeg + it * 64;
        if (Afp) {
            #pragma unroll
            for (int p = 0; p < 4; p++) {
                const int c = p * 256 + tid, r = c >> 4, q = c & 15;
                float4 v  = *(const float4*)&Afp[(size_t)(mBase + r) * lda + ks + q * 4];
                float4 sv = *(const float4*)&sum[ks + q * 4];
                float4 qv = *(const float4*)&sq[ks + q * 4];
                float4 gv = *(const float4*)&g[ks + q * 4];
                float4 bv = *(const float4*)&bt[ks + q * 4];
                ushort4 o;
                o.x = f2bf(bnrelu(v.x, sv.x, qv.x, gv.x, bv.x));
                o.y = f2bf(bnrelu(v.y, sv.y, qv.y, gv.y, bv.y));
                o.z = f2bf(bnrelu(v.z, sv.z, qv.z, gv.z, bv.z));
                o.w = f2bf(bnrelu(v.w, sv.w, qv.w, gv.w, bv.w));
                *(ushort4*)&As[r * 72 + q * 4] = o;
            }
        } else {
            #pragma unroll
            for (int p = 0; p < 2; p++) {
                const int c = p * 256 + tid, r = c >> 3, q = c & 7;
                *(bf16x8*)&As[r * 72 + q * 8] =
                    *(const bf16x8*)&Abf[(size_t)(mBase + r) * lda + ks + q * 8];
            }
        }
        #pragma unroll
        for (int p = 0; p < 2; p++) {
            const int c = p * 256 + tid, r = c >> 3, q = c & 7;
            *(bf16x8*)&Bs[r * 72 + q * 8] =
                *(const bf16x8*)&Bt[(size_t)(nBase + r) * ldb + ks + q * 8];
        }
        __syncthreads();
        #pragma unroll
        for (int kt = 0; kt < 64; kt += 32) {
            bf16x8 af[2], bfr[2];
            #pragma unroll
            for (int mi = 0; mi < 2; mi++)
                af[mi] = *(bf16x8*)&As[(wy * 32 + mi * 16 + l16) * 72 + kt + quad * 8];
            #pragma unroll
            for (int ni = 0; ni < 2; ni++)
                bfr[ni] = *(bf16x8*)&Bs[(wx * 32 + ni * 16 + l16) * 72 + kt + quad * 8];
            #pragma unroll
            for (int mi = 0; mi < 2; mi++)
                #pragma unroll
                for (int ni = 0; ni < 2; ni++)
                    acc[mi][ni] = __builtin_amdgcn_mfma_f32_16x16x32_bf16(
                        af[mi], bfr[ni], acc[mi][ni], 0, 0, 0);
        }
        __syncthreads();
    }
    // C/D layout: col = lane&15, row = quad*4 + e
    #pragma unroll
    for (int mi = 0; mi < 2; mi++)
        #pragma unroll
        for (int ni = 0; ni < 2; ni++) {
            const int gn = nBase + wx * 32 + ni * 16 + l16;
            const int gm0 = mBase + wy * 32 + mi * 16 + quad * 4;
            if (atomicEp) {
                #pragma unroll
                for (int e = 0; e < 4; e++)
                    unsafeAtomicAdd(&C[(size_t)(gm0 + e) * ldc + gn], acc[mi][ni][e]);
            } else {
                float s = 0.f, q = 0.f;
                #pragma unroll
                for (int e = 0; e < 4; e++) {
                    float v = acc[mi][ni][e];
                    C[(size_t)(gm0 + e) * ldc + gn] = v;
                    s += v;
                    q = fmaf(v, v, q);
                }
                if (sumOut) {
                    unsafeAtomicAdd(&sumOut[gn], s);
                    unsafeAtomicAdd(&sqOut[gn], q);
                }
            }
        }
}

__global__ __launch_bounds__(256, 2) void fused_all(
    const float* __restrict__ features, const int* __restrict__ labels,
    const float* __restrict__ W1, const float* __restrict__ g1,
    const float* __restrict__ bt1, const float* __restrict__ W2,
    const float* __restrict__ g2, const float* __restrict__ bt2,
    const float* __restrict__ We1, const float* __restrict__ bwe1,
    const float* __restrict__ We2, const float* __restrict__ bwe2,
    float* __restrict__ out, float* __restrict__ ws)
{
    __shared__ __align__(16) char smraw[18464];
    const int b = blockIdx.x, tid = threadIdx.x;

    float*  x1   = ws;                       // 262144
    float*  x2   = ws + 262144;              // 262144
    float*  hic  = ws + 524288;              // 524288 (hi | hj, ldc=512)
    float*  sum1 = ws + 1048576;             // stats: sum1 sq1 sum2 sq2
    float*  sq1  = sum1 + 256;
    float*  sum2 = sum1 + 512;
    float*  sq2  = sum1 + 768;
    ushort* featbf = (ushort*)(ws + 1049600);   // 1024x2048 bf16
    ushort* Wt1    = (ushort*)(ws + 2098176);   // 256x2048 bf16 [n][k]
    ushort* Wt2    = (ushort*)(ws + 2360320);   // 256x256
    ushort* Wt34   = (ushort*)(ws + 2393088);   // 512x256
    unsigned* bar  = (unsigned*)(ws + 2458624); // zeroed by init_bar kernel

    // ---------- phase 0: convert features, transpose weights, zero x1 ------
    {
        const int base = b * 4096 + tid * 16;
        #pragma unroll
        for (int q = 0; q < 4; q++) {
            float4 v = *(const float4*)&features[base + q * 4];
            ushort4 o;
            o.x = f2bf(v.x); o.y = f2bf(v.y); o.z = f2bf(v.z); o.w = f2bf(v.w);
            *(ushort4*)&featbf[base + q * 4] = o;
        }
        if (b < 176) {
            ushort* T = (ushort*)smraw;
            const float* src; ushort* dst; int Kd, kt, nt;
            if (b < 128)      { src = W1;  dst = Wt1;  Kd = 2048; kt = b >> 2; nt = b & 3; }
            else if (b < 144) { int q = b - 128; src = W2;  dst = Wt2;  Kd = 256; kt = q >> 2; nt = q & 3; }
            else if (b < 160) { int q = b - 144; src = We1; dst = Wt34; Kd = 256; kt = q >> 2; nt = q & 3; }
            else              { int q = b - 160; src = We1 + 65536; dst = Wt34 + 65536;
                                Kd = 256; kt = q >> 2; nt = q & 3; }
            const int k0 = kt * 64, n0 = nt * 64;
            #pragma unroll
            for (int p = 0; p < 4; p++) {
                const int c = p * 256 + tid, r = c >> 4, q2 = c & 15;
                float4 v = *(const float4*)&src[(size_t)(k0 + r) * 256 + n0 + q2 * 4];
                T[(q2 * 4 + 0) * 72 + r] = f2bf(v.x);
                T[(q2 * 4 + 1) * 72 + r] = f2bf(v.y);
                T[(q2 * 4 + 2) * 72 + r] = f2bf(v.z);
                T[(q2 * 4 + 3) * 72 + r] = f2bf(v.w);
            }
            __syncthreads();
            #pragma unroll
            for (int p = 0; p < 2; p++) {
                const int c = p * 256 + tid, r = c >> 3, q2 = c & 7;
                *(bf16x8*)&dst[(size_t)(n0 + r) * Kd + k0 + q2 * 8] =
                    *(bf16x8*)&T[r * 72 + q2 * 8];
            }
        } else {
            // zero x1 (65536 float4); stats zeroed by init_bar
            float4 z = make_float4(0.f, 0.f, 0.f, 0.f);
            const int idx = (b - 176) * 256 + tid;    // 0..86015 covers 65536
            if (idx < 65536) ((float4*)x1)[idx] = z;
        }
    }
    gbar(bar, NBLK);

    // ---------- phase 1: x1 = featbf @ Wt1^T (64 tiles x z8, atomics) ------
    {
        const int z = b >> 6, rem = b & 63;
        gemm_tile(featbf, nullptr, nullptr, nullptr, nullptr, nullptr,
                  Wt1, x1, FEAT, FEAT, HID,
                  (rem >> 2) * 64, (rem & 3) * 64, z * 256, 4, smraw,
                  true, nullptr, nullptr);
    }
    gbar(bar, 2 * NBLK);

    // ---------- phase 2: column stats of x1 ----------
    {
        const int r0 = b * 2;
        float v0 = x1[r0 * HID + tid], v1 = x1[(r0 + 1) * HID + tid];
        unsafeAtomicAdd(&sum1[tid], v0 + v1);
        unsafeAtomicAdd(&sq1[tid], fmaf(v0, v0, v1 * v1));
    }
    gbar(bar, 3 * NBLK);

    // ---- phase 3: x2 = bnrelu(x1) @ Wt2^T (no split-K; stats2 in epilogue) -
    if (b < 64) {
        gemm_tile(nullptr, x1, sum1, sq1, g1, bt1,
                  Wt2, x2, HID, HID, HID,
                  (b >> 2) * 64, (b & 3) * 64, 0, 4, smraw,
                  false, sum2, sq2);
    }
    gbar(bar, 4 * NBLK);

    // ---------- phase 4: hic = bnrelu(x2) @ Wt34^T (128 tiles, stores) -----
    if (b < 128) {
        gemm_tile(nullptr, x2, sum2, sq2, g2, bt2,
                  Wt34, hic, HID, HID, 512,
                  (b >> 3) * 64, (b & 7) * 64, 0, 4, smraw,
                  false, nullptr, nullptr);
    }
    gbar(bar, 5 * NBLK);

    // ---------- phase 5: all-pairs edge weights + node update -------------
    {
        int*   slab  = (int*)smraw;                 // 1024 ints
        float* sacc  = (float*)(smraw + 4096);      // 4 x 256 floats
        float* swsum = (float*)(smraw + 8192);      // 4 floats
        const int lane = tid & 63, wave = tid >> 6;
        for (int t = tid; t < N_PTS; t += 256) slab[t] = labels[t];

        // per-lane BN2 scale/shift for cols 4*lane..4*lane+3
        float4 sv = *(const float4*)&sum2[lane * 4];
        float4 qv = *(const float4*)&sq2[lane * 4];
        float4 gv = *(const float4*)&g2[lane * 4];
        float4 bv = *(const float4*)&bt2[lane * 4];
        float4 sc, sh;
        {
            float m, var;
            m = sv.x * (1.f/1024.f); var = fmaf(-m, m, qv.x * (1.f/1024.f));
            sc.x = gv.x * rsqrtf(var + 1e-5f); sh.x = fmaf(-sc.x, m, bv.x);
            m = sv.y * (1.f/1024.f); var = fmaf(-m, m, qv.y * (1.f/1024.f));
            sc.y = gv.y * rsqrtf(var + 1e-5f); sh.y = fmaf(-sc.y, m, bv.y);
            m = sv.z * (1.f/1024.f); var = fmaf(-m, m, qv.z * (1.f/1024.f));
            sc.z = gv.z * rsqrtf(var + 1e-5f); sh.z = fmaf(-sc.z, m, bv.z);
            m = sv.w * (1.f/1024.f); var = fmaf(-m, m, qv.w * (1.f/1024.f));
            sc.w = gv.w * rsqrtf(var + 1e-5f); sh.w = fmaf(-sc.w, m, bv.w);
        }
        float4 bw = ((const float4*)bwe1)[lane];
        float4 w2 = ((const float4*)We2)[lane];
        const float b2 = bwe2[0];
        __syncthreads();

        for (int ii = 0; ii < 2; ii++) {
            const int i = b * 2 + ii;
            const int myLab = slab[i];
            float4 hv_i = *(const float4*)&hic[(size_t)i * 512 + lane * 4];
            const float hb0 = hv_i.x + bw.x, hb1 = hv_i.y + bw.y;
            const float hb2 = hv_i.z + bw.z, hb3 = hv_i.w + bw.w;

            float a0 = 0.f, a1 = 0.f, a2 = 0.f, a3 = 0.f, wsum = 0.f;
            for (int chunk = wave * 64; chunk < N_PTS; chunk += 256) {
                const int j = chunk + lane;
                const bool match = (slab[j] == myLab) && (j != i);
                unsigned long long mask = __ballot(match);
                while (mask) {
                    const int p0i = __builtin_ctzll(mask);
                    mask &= mask - 1;
                    const int jj0 = chunk + p0i;
                    const bool dual = (mask != 0ull);
                    int jj1 = jj0;
                    if (dual) {
                        const int p1i = __builtin_ctzll(mask);
                        mask &= mask - 1;
                        jj1 = chunk + p1i;
                    }
                    float4 hv0 = *(const float4*)&hic[(size_t)jj0 * 512 + 256 + lane * 4];
                    float4 hv1 = *(const float4*)&hic[(size_t)jj1 * 512 + 256 + lane * 4];
                    float p0 = fmaxf(hb0 + hv0.x, 0.f) * w2.x
                             + fmaxf(hb1 + hv0.y, 0.f) * w2.y
                             + fmaxf(hb2 + hv0.z, 0.f) * w2.z
                             + fmaxf(hb3 + hv0.w, 0.f) * w2.w;
                    float p1 = fmaxf(hb0 + hv1.x, 0.f) * w2.x
                             + fmaxf(hb1 + hv1.y, 0.f) * w2.y
                             + fmaxf(hb2 + hv1.z, 0.f) * w2.z
                             + fmaxf(hb3 + hv1.w, 0.f) * w2.w;
                    #pragma unroll
                    for (int off = 1; off < 64; off <<= 1) {
                        p0 += __shfl_xor(p0, off, 64);
                        p1 += __shfl_xor(p1, off, 64);
                    }
                    const float w0 = 1.f / (1.f + expf(-(p0 + b2)));
                    const float w1 = dual ? 1.f / (1.f + expf(-(p1 + b2))) : 0.f;
                    float4 xv0 = *(const float4*)&x2[(size_t)jj0 * HID + lane * 4];
                    float4 xv1 = *(const float4*)&x2[(size_t)jj1 * HID + lane * 4];
                    a0 = fmaf(w0, fmaxf(fmaf(xv0.x, sc.x, sh.x), 0.f),
                         fmaf(w1, fmaxf(fmaf(xv1.x, sc.x, sh.x), 0.f), a0));
                    a1 = fmaf(w0, fmaxf(fmaf(xv0.y, sc.y, sh.y), 0.f),
                         fmaf(w1, fmaxf(fmaf(xv1.y, sc.y, sh.y), 0.f), a1));
                    a2 = fmaf(w0, fmaxf(fmaf(xv0.z, sc.z, sh.z), 0.f),
                         fmaf(w1, fmaxf(fmaf(xv1.z, sc.z, sh.z), 0.f), a2));
                    a3 = fmaf(w0, fmaxf(fmaf(xv0.w, sc.w, sh.w), 0.f),
                         fmaf(w1, fmaxf(fmaf(xv1.w, sc.w, sh.w), 0.f), a3));
                    wsum += w0 + w1;
                }
            }
            ((float4*)&sacc[wave * HID])[lane] = make_float4(a0, a1, a2, a3);
            if (lane == 0) swsum[wave] = wsum;
            __syncthreads();
            const float at = sacc[tid] + sacc[HID + tid] +
                             sacc[2 * HID + tid] + sacc[3 * HID + tid];
            const float wt = swsum[0] + swsum[1] + swsum[2] + swsum[3];
            float m  = sum2[tid] * (1.f/1024.f);
            float vr = fmaf(-m, m, sq2[tid] * (1.f/1024.f));
            float s  = g2[tid] * rsqrtf(vr + 1e-5f);
            float di_i = fmaxf(fmaf(x2[(size_t)i * HID + tid], s,
                                    fmaf(-s, m, bt2[tid])), 0.f);
            out[(size_t)i * HID + tid] = di_i + (wt > 0.f ? at / wt : 0.f);
            __syncthreads();
        }
    }
}

extern "C" void kernel_launch(void* const* d_in, const int* in_sizes, int n_in,
                              void* d_out, int out_size, void* d_ws, size_t ws_size,
                              hipStream_t stream)
{
    const float* features = (const float*)d_in[0];
    const int*   labels   = (const int*)d_in[1];
    const float* W1   = (const float*)d_in[2];
    // b1/b2 cancel exactly through train-mode BN (mean subtraction)
    const float* g1   = (const float*)d_in[4];
    const float* bt1  = (const float*)d_in[5];
    const float* W2   = (const float*)d_in[6];
    const float* g2   = (const float*)d_in[8];
    const float* bt2  = (const float*)d_in[9];
    const float* We1  = (const float*)d_in[10];
    const float* bwe1 = (const float*)d_in[11];
    const float* We2  = (const float*)d_in[12];
    const float* bwe2 = (const float*)d_in[13];
    float* out = (float*)d_out;
    float* wsp = (float*)d_ws;

    unsigned* bar = (unsigned*)(wsp + 2458624);
    float* stats  = wsp + 1048576;

    // zero barrier counter + stats via a kernel (stream-ordered, capturable)
    init_bar<<<1, 256, 0, stream>>>(bar, stats);

    void* kargs[] = { &features, &labels, &W1, &g1, &bt1, &W2, &g2, &bt2,
                      &We1, &bwe1, &We2, &bwe2, &out, &wsp };
    hipError_t e = hipLaunchCooperativeKernel((const void*)fused_all,
                                              dim3(NBLK), dim3(256),
                                              kargs, 0, stream);
    if (e != hipSuccess) {
        // fallback: regular launch; launch_bounds(256,2) guarantees 2 blk/CU
        // x 256 CUs = 512 co-resident, so the spin barrier cannot deadlock.
        fused_all<<<dim3(NBLK), dim3(256), 0, stream>>>(
            features, labels, W1, g1, bt1, W2, g2, bt2,
            We1, bwe1, We2, bwe2, out, wsp);
    }
}

// Round 8
// 334.425 us; speedup vs baseline: 1.4922x; 1.4518x over previous
//
#include <hip/hip_runtime.h>
#include <math.h>

#define N_PTS 1024
#define HID   256
#define FEAT  2048
#define NBLK  512

typedef short bf16x8 __attribute__((ext_vector_type(8)));
typedef float f32x4  __attribute__((ext_vector_type(4)));

__device__ inline ushort f2bf(float f) {
    union { float f; unsigned u; } v; v.f = f;
    unsigned r = v.u + 0x7fff + ((v.u >> 16) & 1);   // round-to-nearest-even
    return (ushort)(r >> 16);
}

// train-mode BN (biased var) + ReLU from raw column sums
__device__ inline float bnrelu(float v, float s, float q, float g, float b) {
    float m   = s * (1.f / 1024.f);
    float var = fmaf(-m, m, q * (1.f / 1024.f));
    float sc  = g * rsqrtf(var + 1e-5f);
    return fmaxf(fmaf(v, sc, fmaf(-sc, m, b)), 0.f);
}

// grid barrier with RELAXED spin: acquire-spins invalidate per-XCD caches
// every iteration (r5/r7 evidence: 395-399us regardless of barrier count);
// relaxed atomic load bypasses caches without maintenance ops. One release
// fence before arrive, one acquire fence after exit.
__device__ __forceinline__ void gbar(unsigned* bar, unsigned target) {
    __syncthreads();
    if (threadIdx.x == 0) {
        __builtin_amdgcn_fence(__ATOMIC_RELEASE, "agent");
        __hip_atomic_fetch_add(bar, 1u, __ATOMIC_RELAXED, __HIP_MEMORY_SCOPE_AGENT);
        while (__hip_atomic_load(bar, __ATOMIC_RELAXED, __HIP_MEMORY_SCOPE_AGENT) < target)
            __builtin_amdgcn_s_sleep(8);
        __builtin_amdgcn_fence(__ATOMIC_ACQUIRE, "agent");
    }
    __syncthreads();
}

// zero barrier counter + stats (sum1,sq1,sum2,sq2 = 1024 floats)
__global__ void init_bar(unsigned* __restrict__ bar, float* __restrict__ stats) {
    ((float4*)stats)[threadIdx.x] = make_float4(0.f, 0.f, 0.f, 0.f);
    if (threadIdx.x == 0) *bar = 0u;
}

// one 64x64 output tile, BK=64, 4 waves in 2x2. Optional BN+ReLU on A from
// raw stats. B pre-transposed bf16 [n][ldb].
// atomicEp=true: unsafeAtomicAdd (split-K). false: plain store, plus exact
// column stats (sum/sumsq) into sumOut/sqOut if non-null (final values).
__device__ void gemm_tile(
    const ushort* __restrict__ Abf, const float* __restrict__ Afp,
    const float* __restrict__ sum, const float* __restrict__ sq,
    const float* __restrict__ g, const float* __restrict__ bt,
    const ushort* __restrict__ Bt, float* __restrict__ C,
    int lda, int ldb, int ldc, int mBase, int nBase, int kBeg, int kIters,
    char* smraw, bool atomicEp, float* sumOut, float* sqOut)
{
    ushort* As = (ushort*)smraw;            // 64*72 ushorts
    ushort* Bs = (ushort*)(smraw + 9216);
    const int tid  = threadIdx.x;
    const int lane = tid & 63, wave = tid >> 6;
    const int wy = wave >> 1, wx = wave & 1;
    const int quad = lane >> 4, l16 = lane & 15;

    f32x4 acc[2][2] = {};

    for (int it = 0; it < kIters; ++it) {
        const int ks = kBeg + it * 64;
        if (Afp) {
            #pragma unroll
            for (int p = 0; p < 4; p++) {
                const int c = p * 256 + tid, r = c >> 4, q = c & 15;
                float4 v  = *(const float4*)&Afp[(size_t)(mBase + r) * lda + ks + q * 4];
                float4 sv = *(const float4*)&sum[ks + q * 4];
                float4 qv = *(const float4*)&sq[ks + q * 4];
                float4 gv = *(const float4*)&g[ks + q * 4];
                float4 bv = *(const float4*)&bt[ks + q * 4];
                ushort4 o;
                o.x = f2bf(bnrelu(v.x, sv.x, qv.x, gv.x, bv.x));
                o.y = f2bf(bnrelu(v.y, sv.y, qv.y, gv.y, bv.y));
                o.z = f2bf(bnrelu(v.z, sv.z, qv.z, gv.z, bv.z));
                o.w = f2bf(bnrelu(v.w, sv.w, qv.w, gv.w, bv.w));
                *(ushort4*)&As[r * 72 + q * 4] = o;
            }
        } else {
            #pragma unroll
            for (int p = 0; p < 2; p++) {
                const int c = p * 256 + tid, r = c >> 3, q = c & 7;
                *(bf16x8*)&As[r * 72 + q * 8] =
                    *(const bf16x8*)&Abf[(size_t)(mBase + r) * lda + ks + q * 8];
            }
        }
        #pragma unroll
        for (int p = 0; p < 2; p++) {
            const int c = p * 256 + tid, r = c >> 3, q = c & 7;
            *(bf16x8*)&Bs[r * 72 + q * 8] =
                *(const bf16x8*)&Bt[(size_t)(nBase + r) * ldb + ks + q * 8];
        }
        __syncthreads();
        #pragma unroll
        for (int kt = 0; kt < 64; kt += 32) {
            bf16x8 af[2], bfr[2];
            #pragma unroll
            for (int mi = 0; mi < 2; mi++)
                af[mi] = *(bf16x8*)&As[(wy * 32 + mi * 16 + l16) * 72 + kt + quad * 8];
            #pragma unroll
            for (int ni = 0; ni < 2; ni++)
                bfr[ni] = *(bf16x8*)&Bs[(wx * 32 + ni * 16 + l16) * 72 + kt + quad * 8];
            #pragma unroll
            for (int mi = 0; mi < 2; mi++)
                #pragma unroll
                for (int ni = 0; ni < 2; ni++)
                    acc[mi][ni] = __builtin_amdgcn_mfma_f32_16x16x32_bf16(
                        af[mi], bfr[ni], acc[mi][ni], 0, 0, 0);
        }
        __syncthreads();
    }
    // C/D layout: col = lane&15, row = quad*4 + e
    #pragma unroll
    for (int mi = 0; mi < 2; mi++)
        #pragma unroll
        for (int ni = 0; ni < 2; ni++) {
            const int gn = nBase + wx * 32 + ni * 16 + l16;
            const int gm0 = mBase + wy * 32 + mi * 16 + quad * 4;
            if (atomicEp) {
                #pragma unroll
                for (int e = 0; e < 4; e++)
                    unsafeAtomicAdd(&C[(size_t)(gm0 + e) * ldc + gn], acc[mi][ni][e]);
            } else {
                float s = 0.f, q = 0.f;
                #pragma unroll
                for (int e = 0; e < 4; e++) {
                    float v = acc[mi][ni][e];
                    C[(size_t)(gm0 + e) * ldc + gn] = v;
                    s += v;
                    q = fmaf(v, v, q);
                }
                if (sumOut) {
                    unsafeAtomicAdd(&sumOut[gn], s);
                    unsafeAtomicAdd(&sqOut[gn], q);
                }
            }
        }
}

__global__ __launch_bounds__(256, 2) void fused_all(
    const float* __restrict__ features, const int* __restrict__ labels,
    const float* __restrict__ W1, const float* __restrict__ g1,
    const float* __restrict__ bt1, const float* __restrict__ W2,
    const float* __restrict__ g2, const float* __restrict__ bt2,
    const float* __restrict__ We1, const float* __restrict__ bwe1,
    const float* __restrict__ We2, const float* __restrict__ bwe2,
    float* __restrict__ out, float* __restrict__ ws)
{
    __shared__ __align__(16) char smraw[18464];
    const int b = blockIdx.x, tid = threadIdx.x;

    float*  x1   = ws;                       // 262144
    float*  x2   = ws + 262144;              // 262144
    float*  hic  = ws + 524288;              // 524288 (hi | hj, ldc=512)
    float*  sum1 = ws + 1048576;             // stats: sum1 sq1 sum2 sq2
    float*  sq1  = sum1 + 256;
    float*  sum2 = sum1 + 512;
    float*  sq2  = sum1 + 768;
    ushort* featbf = (ushort*)(ws + 1049600);   // 1024x2048 bf16
    ushort* Wt1    = (ushort*)(ws + 2098176);   // 256x2048 bf16 [n][k]
    ushort* Wt2    = (ushort*)(ws + 2360320);   // 256x256
    ushort* Wt34   = (ushort*)(ws + 2393088);   // 512x256
    unsigned* bar  = (unsigned*)(ws + 2458624); // zeroed by init_bar kernel

    // ---------- phase 0: convert features, transpose weights, zero x1 ------
    {
        const int base = b * 4096 + tid * 16;
        #pragma unroll
        for (int q = 0; q < 4; q++) {
            float4 v = *(const float4*)&features[base + q * 4];
            ushort4 o;
            o.x = f2bf(v.x); o.y = f2bf(v.y); o.z = f2bf(v.z); o.w = f2bf(v.w);
            *(ushort4*)&featbf[base + q * 4] = o;
        }
        if (b < 176) {
            ushort* T = (ushort*)smraw;
            const float* src; ushort* dst; int Kd, kt, nt;
            if (b < 128)      { src = W1;  dst = Wt1;  Kd = 2048; kt = b >> 2; nt = b & 3; }
            else if (b < 144) { int q = b - 128; src = W2;  dst = Wt2;  Kd = 256; kt = q >> 2; nt = q & 3; }
            else if (b < 160) { int q = b - 144; src = We1; dst = Wt34; Kd = 256; kt = q >> 2; nt = q & 3; }
            else              { int q = b - 160; src = We1 + 65536; dst = Wt34 + 65536;
                                Kd = 256; kt = q >> 2; nt = q & 3; }
            const int k0 = kt * 64, n0 = nt * 64;
            #pragma unroll
            for (int p = 0; p < 4; p++) {
                const int c = p * 256 + tid, r = c >> 4, q2 = c & 15;
                float4 v = *(const float4*)&src[(size_t)(k0 + r) * 256 + n0 + q2 * 4];
                T[(q2 * 4 + 0) * 72 + r] = f2bf(v.x);
                T[(q2 * 4 + 1) * 72 + r] = f2bf(v.y);
                T[(q2 * 4 + 2) * 72 + r] = f2bf(v.z);
                T[(q2 * 4 + 3) * 72 + r] = f2bf(v.w);
            }
            __syncthreads();
            #pragma unroll
            for (int p = 0; p < 2; p++) {
                const int c = p * 256 + tid, r = c >> 3, q2 = c & 7;
                *(bf16x8*)&dst[(size_t)(n0 + r) * Kd + k0 + q2 * 8] =
                    *(bf16x8*)&T[r * 72 + q2 * 8];
            }
        } else {
            // zero x1 (65536 float4); stats zeroed by init_bar
            float4 z = make_float4(0.f, 0.f, 0.f, 0.f);
            const int idx = (b - 176) * 256 + tid;    // 0..86015 covers 65536
            if (idx < 65536) ((float4*)x1)[idx] = z;
        }
    }
    gbar(bar, NBLK);

    // ---------- phase 1: x1 = featbf @ Wt1^T (64 tiles x z8, atomics) ------
    {
        const int z = b >> 6, rem = b & 63;
        gemm_tile(featbf, nullptr, nullptr, nullptr, nullptr, nullptr,
                  Wt1, x1, FEAT, FEAT, HID,
                  (rem >> 2) * 64, (rem & 3) * 64, z * 256, 4, smraw,
                  true, nullptr, nullptr);
    }
    gbar(bar, 2 * NBLK);

    // ---------- phase 2: column stats of x1 ----------
    {
        const int r0 = b * 2;
        float v0 = x1[r0 * HID + tid], v1 = x1[(r0 + 1) * HID + tid];
        unsafeAtomicAdd(&sum1[tid], v0 + v1);
        unsafeAtomicAdd(&sq1[tid], fmaf(v0, v0, v1 * v1));
    }
    gbar(bar, 3 * NBLK);

    // ---- phase 3: x2 = bnrelu(x1) @ Wt2^T (no split-K; stats2 in epilogue) -
    if (b < 64) {
        gemm_tile(nullptr, x1, sum1, sq1, g1, bt1,
                  Wt2, x2, HID, HID, HID,
                  (b >> 2) * 64, (b & 3) * 64, 0, 4, smraw,
                  false, sum2, sq2);
    }
    gbar(bar, 4 * NBLK);

    // ---------- phase 4: hic = bnrelu(x2) @ Wt34^T (128 tiles, stores) -----
    if (b < 128) {
        gemm_tile(nullptr, x2, sum2, sq2, g2, bt2,
                  Wt34, hic, HID, HID, 512,
                  (b >> 3) * 64, (b & 7) * 64, 0, 4, smraw,
                  false, nullptr, nullptr);
    }
    gbar(bar, 5 * NBLK);

    // ---------- phase 5: all-pairs edge weights + node update -------------
    {
        int*   slab  = (int*)smraw;                 // 1024 ints
        float* sacc  = (float*)(smraw + 4096);      // 4 x 256 floats
        float* swsum = (float*)(smraw + 8192);      // 4 floats
        const int lane = tid & 63, wave = tid >> 6;
        for (int t = tid; t < N_PTS; t += 256) slab[t] = labels[t];

        // per-lane BN2 scale/shift for cols 4*lane..4*lane+3
        float4 sv = *(const float4*)&sum2[lane * 4];
        float4 qv = *(const float4*)&sq2[lane * 4];
        float4 gv = *(const float4*)&g2[lane * 4];
        float4 bv = *(const float4*)&bt2[lane * 4];
        float4 sc, sh;
        {
            float m, var;
            m = sv.x * (1.f/1024.f); var = fmaf(-m, m, qv.x * (1.f/1024.f));
            sc.x = gv.x * rsqrtf(var + 1e-5f); sh.x = fmaf(-sc.x, m, bv.x);
            m = sv.y * (1.f/1024.f); var = fmaf(-m, m, qv.y * (1.f/1024.f));
            sc.y = gv.y * rsqrtf(var + 1e-5f); sh.y = fmaf(-sc.y, m, bv.y);
            m = sv.z * (1.f/1024.f); var = fmaf(-m, m, qv.z * (1.f/1024.f));
            sc.z = gv.z * rsqrtf(var + 1e-5f); sh.z = fmaf(-sc.z, m, bv.z);
            m = sv.w * (1.f/1024.f); var = fmaf(-m, m, qv.w * (1.f/1024.f));
            sc.w = gv.w * rsqrtf(var + 1e-5f); sh.w = fmaf(-sc.w, m, bv.w);
        }
        float4 bw = ((const float4*)bwe1)[lane];
        float4 w2 = ((const float4*)We2)[lane];
        const float b2 = bwe2[0];
        __syncthreads();

        for (int ii = 0; ii < 2; ii++) {
            const int i = b * 2 + ii;
            const int myLab = slab[i];
            float4 hv_i = *(const float4*)&hic[(size_t)i * 512 + lane * 4];
            const float hb0 = hv_i.x + bw.x, hb1 = hv_i.y + bw.y;
            const float hb2 = hv_i.z + bw.z, hb3 = hv_i.w + bw.w;

            float a0 = 0.f, a1 = 0.f, a2 = 0.f, a3 = 0.f, wsum = 0.f;
            for (int chunk = wave * 64; chunk < N_PTS; chunk += 256) {
                const int j = chunk + lane;
                const bool match = (slab[j] == myLab) && (j != i);
                unsigned long long mask = __ballot(match);
                while (mask) {
                    const int p0i = __builtin_ctzll(mask);
                    mask &= mask - 1;
                    const int jj0 = chunk + p0i;
                    const bool dual = (mask != 0ull);
                    int jj1 = jj0;
                    if (dual) {
                        const int p1i = __builtin_ctzll(mask);
                        mask &= mask - 1;
                        jj1 = chunk + p1i;
                    }
                    float4 hv0 = *(const float4*)&hic[(size_t)jj0 * 512 + 256 + lane * 4];
                    float4 hv1 = *(const float4*)&hic[(size_t)jj1 * 512 + 256 + lane * 4];
                    float p0 = fmaxf(hb0 + hv0.x, 0.f) * w2.x
                             + fmaxf(hb1 + hv0.y, 0.f) * w2.y
                             + fmaxf(hb2 + hv0.z, 0.f) * w2.z
                             + fmaxf(hb3 + hv0.w, 0.f) * w2.w;
                    float p1 = fmaxf(hb0 + hv1.x, 0.f) * w2.x
                             + fmaxf(hb1 + hv1.y, 0.f) * w2.y
                             + fmaxf(hb2 + hv1.z, 0.f) * w2.z
                             + fmaxf(hb3 + hv1.w, 0.f) * w2.w;
                    #pragma unroll
                    for (int off = 1; off < 64; off <<= 1) {
                        p0 += __shfl_xor(p0, off, 64);
                        p1 += __shfl_xor(p1, off, 64);
                    }
                    const float w0 = 1.f / (1.f + expf(-(p0 + b2)));
                    const float w1 = dual ? 1.f / (1.f + expf(-(p1 + b2))) : 0.f;
                    float4 xv0 = *(const float4*)&x2[(size_t)jj0 * HID + lane * 4];
                    float4 xv1 = *(const float4*)&x2[(size_t)jj1 * HID + lane * 4];
                    a0 = fmaf(w0, fmaxf(fmaf(xv0.x, sc.x, sh.x), 0.f),
                         fmaf(w1, fmaxf(fmaf(xv1.x, sc.x, sh.x), 0.f), a0));
                    a1 = fmaf(w0, fmaxf(fmaf(xv0.y, sc.y, sh.y), 0.f),
                         fmaf(w1, fmaxf(fmaf(xv1.y, sc.y, sh.y), 0.f), a1));
                    a2 = fmaf(w0, fmaxf(fmaf(xv0.z, sc.z, sh.z), 0.f),
                         fmaf(w1, fmaxf(fmaf(xv1.z, sc.z, sh.z), 0.f), a2));
                    a3 = fmaf(w0, fmaxf(fmaf(xv0.w, sc.w, sh.w), 0.f),
                         fmaf(w1, fmaxf(fmaf(xv1.w, sc.w, sh.w), 0.f), a3));
                    wsum += w0 + w1;
                }
            }
            ((float4*)&sacc[wave * HID])[lane] = make_float4(a0, a1, a2, a3);
            if (lane == 0) swsum[wave] = wsum;
            __syncthreads();
            const float at = sacc[tid] + sacc[HID + tid] +
                             sacc[2 * HID + tid] + sacc[3 * HID + tid];
            const float wt = swsum[0] + swsum[1] + swsum[2] + swsum[3];
            float m  = sum2[tid] * (1.f/1024.f);
            float vr = fmaf(-m, m, sq2[tid] * (1.f/1024.f));
            float s  = g2[tid] * rsqrtf(vr + 1e-5f);
            float di_i = fmaxf(fmaf(x2[(size_t)i * HID + tid], s,
                                    fmaf(-s, m, bt2[tid])), 0.f);
            out[(size_t)i * HID + tid] = di_i + (wt > 0.f ? at / wt : 0.f);
            __syncthreads();
        }
    }
}

extern "C" void kernel_launch(void* const* d_in, const int* in_sizes, int n_in,
                              void* d_out, int out_size, void* d_ws, size_t ws_size,
                              hipStream_t stream)
{
    const float* features = (const float*)d_in[0];
    const int*   labels   = (const int*)d_in[1];
    const float* W1   = (const float*)d_in[2];
    // b1/b2 cancel exactly through train-mode BN (mean subtraction)
    const float* g1   = (const float*)d_in[4];
    const float* bt1  = (const float*)d_in[5];
    const float* W2   = (const float*)d_in[6];
    const float* g2   = (const float*)d_in[8];
    const float* bt2  = (const float*)d_in[9];
    const float* We1  = (const float*)d_in[10];
    const float* bwe1 = (const float*)d_in[11];
    const float* We2  = (const float*)d_in[12];
    const float* bwe2 = (const float*)d_in[13];
    float* out = (float*)d_out;
    float* wsp = (float*)d_ws;

    unsigned* bar = (unsigned*)(wsp + 2458624);
    float* stats  = wsp + 1048576;

    // zero barrier counter + stats via a kernel (stream-ordered, capturable)
    init_bar<<<1, 256, 0, stream>>>(bar, stats);

    void* kargs[] = { &features, &labels, &W1, &g1, &bt1, &W2, &g2, &bt2,
                      &We1, &bwe1, &We2, &bwe2, &out, &wsp };
    hipError_t e = hipLaunchCooperativeKernel((const void*)fused_all,
                                              dim3(NBLK), dim3(256),
                                              kargs, 0, stream);
    if (e != hipSuccess) {
        // fallback: regular launch; launch_bounds(256,2) guarantees 2 blk/CU
        // x 256 CUs = 512 co-resident, so the spin barrier cannot deadlock.
        fused_all<<<dim3(NBLK), dim3(256), 0, stream>>>(
            features, labels, W1, g1, bt1, W2, g2, bt2,
            We1, bwe1, We2, bwe2, out, wsp);
    }
}